// Round 7
// baseline (197.143 us; speedup 1.0000x reference)
//
#include <hip/hip_runtime.h>
#include <stdint.h>
#include <stddef.h>

// CliffordLinear as one bf16 GEMM:
//   out[b, o*8+l] = sum_{i,k} X[b, i*8+k] * Wt[o*8+l, i*8+k] + bias[o*8+l]
//   Wt[(o,l),(i,k)] = sum_j cayley[j,k,l] * W[o,i,j]
// M=8192, N=2048, K=2048. bf16 MFMA (32x32x16), fp32 accumulate.
//
// R13b: identical to R13 (round 6 bench was an infra failure -- container
// failed twice, no kernel verdict; source re-audited for hang causes:
// barrier uniformity, waitcnt reachability, OOB -- all clean). Resubmit.
//
// R13: attack the ~100 us NON-GEMM bucket (constant across R7-R12; the GEMM
// dispatch is only ~75 us of the ~180 us total). The X cast kernel (64 MB
// read + 32 MB write + a dispatch) is ELIMINATED: the GEMM reg-stages A
// directly from f32 -- coalesced 64 B/lane f32x4 loads (issued one window
// early, T14 split), cvt to bf16, ds_write_b128 into the SAME verified
// blocked LDS layout ([4 kg][256 row][8]) that R12's DMA produced. B (folded
// W, bf16) still stages via global_load_lds. Prep shrinks to a fold-only
// kernel (8 MB): W rows staged through LDS (coalesced reads), blocked
// coalesced writes.
// vmcnt accounting re-derived for the mixed queue (A f32 loads + B DMA):
// per-slice issue order [h0: 4x A(s+3)][h1: 2x B(s+3)]; at h1 entry
// vmcnt(6) == {B(s+2), A(s+3)} in flight => A(s+2) regs ready AND all B
// through B(s+1) landed. lgkmcnt(0) before each h1-end barrier makes the
// cvt ds_writes visible cross-wave (raw s_barrier does not drain DS).
// GEMM core otherwise = R12 (equal-best): 32x32x16 MFMA, ring-4 slots,
// ping-pong frag regs, setprio, XCD swizzle, 0 bank conflicts.

typedef __bf16 bf16x8 __attribute__((ext_vector_type(8)));
typedef float  f32x4  __attribute__((ext_vector_type(4)));
typedef float  f32x16 __attribute__((ext_vector_type(16)));

#define BM 256
#define BN 256
#define SLOT 8192           // elems per slot (16 KB): [4 kg][256 rc][8]

__device__ __forceinline__ void async_copy16(void* lds_dst, const void* g_src) {
    __builtin_amdgcn_global_load_lds(
        (__attribute__((address_space(1))) void*)g_src,
        (__attribute__((address_space(3))) void*)lds_dst,
        16, 0, 0);
}

__device__ __forceinline__ bf16x8 cvt2(f32x4 a, f32x4 b) {
    bf16x8 r;
    r[0] = (__bf16)a[0]; r[1] = (__bf16)a[1];
    r[2] = (__bf16)a[2]; r[3] = (__bf16)a[3];
    r[4] = (__bf16)b[0]; r[5] = (__bf16)b[1];
    r[6] = (__bf16)b[2]; r[7] = (__bf16)b[3];
    return r;
}

// ---------------- kernel 1: fold Cayley into W (blocked bf16 layout) ------
// Block b: i = b>>3 (Cin idx), n0 = (b&7)*256. Stage the 32 W-rows this
// block needs (o = n0/8 .. +31) into LDS (coalesced f32x4), then each thread
// computes one n = (o,l) column octet and writes 16 B, consecutive threads
// -> consecutive addresses (coalesced). Output layout identical to R12's
// verified Wt2: [n>>8][i][n&255][8].
__global__ __launch_bounds__(256) void fold_kernel(
    const float* __restrict__ W, const float* __restrict__ cayley,
    __bf16* __restrict__ Wt2, int Cin, int N, int K)
{
    __shared__ float Cay[512];
    __shared__ float Wl[32][8];
    const int b  = blockIdx.x;
    const int i  = b >> 3;
    const int n0 = (b & 7) * 256;
    const int o0 = n0 >> 3;

    for (int t = threadIdx.x; t < 512; t += 256) Cay[t] = cayley[t];
    if (threadIdx.x < 64) {
        int o2 = threadIdx.x >> 1, half = threadIdx.x & 1;
        *(f32x4*)&Wl[o2][half * 4] =
            *(const f32x4*)(W + ((size_t)(o0 + o2) * Cin + i) * 8 + half * 4);
    }
    __syncthreads();

    const int t  = threadIdx.x;
    const int o2 = t >> 3, l = t & 7;
    float w8[8];
    #pragma unroll
    for (int j = 0; j < 8; ++j) w8[j] = Wl[o2][j];

    bf16x8 outv;
    #pragma unroll
    for (int k = 0; k < 8; ++k) {
        float s = 0.f;
        #pragma unroll
        for (int j = 0; j < 8; ++j) s += Cay[j * 64 + k * 8 + l] * w8[j];
        outv[k] = (__bf16)s;
    }
    const int n = n0 + t;
    *(bf16x8*)(Wt2 + (size_t)(n >> 8) * (size_t)K * 256
                   + (size_t)i * 2048 + (size_t)(n & 255) * 8) = outv;
}

// ---------------- kernel 2: bf16 GEMM, 32x32x16 MFMA ----------------------
// X  : [M][K] f32 (raw input; A reg-staged + cvt in-kernel)
// B2 : [N/256][K/8][256 cols][8] bf16 blocked (fold output)
// C  : [M][N] fp32
// LDS slot = [4 kg][256 rc][8] = 16 KB (R12-verified layout & frag reads).
// A staging: thread t covers row=t>>1, kh=t&1: 16 contiguous f32 (64 B,
// coalesced 128 B per row-pair) -> 2 ds_write_b128 to kg=2kh,2kh+1.
__global__ __launch_bounds__(512, 2) void gemm_bt_kernel(
    const float*  __restrict__ X,
    const __bf16* __restrict__ B2,
    const float*  __restrict__ bias,
    float* __restrict__ C,
    int M, int N, int K)
{
    __shared__ __align__(16) __bf16 As[4][SLOT];  // 4 x 16 KB
    __shared__ __align__(16) __bf16 Bs[4][SLOT];  // 4 x 16 KB

    const int tid  = threadIdx.x;
    const int wave = tid >> 6;    // 0..7
    const int lane = tid & 63;
    const int l31  = lane & 31;
    const int lhi  = lane >> 5;

    // --- XCD swizzle: 256 blocks, 8 XCDs; bijective since 256%8==0.
    const int bid = blockIdx.x;
    const int xcd = bid & 7;
    const int idx = bid >> 3;                 // 0..31
    const int mBase = (xcd * 4 + (idx & 3)) * BM;
    const int nBase = (idx >> 2) * BN;

    // --- A staging addressing (f32 direct)
    const int arow = tid >> 1;            // 0..255
    const int akh  = tid & 1;             // k half (16 f32)
    const float* gX = X + (size_t)(mBase + arow) * K + akh * 16;
    const int wd0 = (2 * akh) * 2048 + arow * 8;   // LDS elem offset kg=2kh
    const int wd1 = wd0 + 2048;                    // kg=2kh+1

    // --- B staging: wave w owns chunks 2w, 2w+1 (1 KB each) of the slice.
    const int c0 = 2 * wave, c1 = 2 * wave + 1;
    const __bf16* gB0 = B2 + (size_t)nBase * K + c0 * 512 + lane * 8;
    const __bf16* gB1 = B2 + (size_t)nBase * K + c1 * 512 + lane * 8;
    const int dstB0 = c0 * 512, dstB1 = c1 * 512;

#define ISSUE_A(SET, q) do {                                   \
        SET[0] = *(const f32x4*)(gX + (size_t)(q) * 32);       \
        SET[1] = *(const f32x4*)(gX + (size_t)(q) * 32 + 4);   \
        SET[2] = *(const f32x4*)(gX + (size_t)(q) * 32 + 8);   \
        SET[3] = *(const f32x4*)(gX + (size_t)(q) * 32 + 12);  \
    } while (0)
#define CVT_WRITE(SET, slot) do {                              \
        *(bf16x8*)&As[slot][wd0] = cvt2(SET[0], SET[1]);       \
        *(bf16x8*)&As[slot][wd1] = cvt2(SET[2], SET[3]);       \
    } while (0)
#define STAGE_B(slot, q) do {                                              \
        async_copy16(&Bs[slot][dstB0], gB0 + (size_t)(q) * 8192);          \
        async_copy16(&Bs[slot][dstB1], gB1 + (size_t)(q) * 8192);          \
    } while (0)

    // --- compute: wave (wm,wn) owns 128x64; 4x2 tiles of 32x32.
    const int wm = wave >> 2;     // 0..1
    const int wn = wave & 3;      // 0..3
    const __bf16* paBase = &As[0][lhi * 2048 + (wm * 128 + l31) * 8];
    const __bf16* pbBase = &Bs[0][lhi * 2048 + (wn * 64  + l31) * 8];

    f32x16 acc[4][2] = {};
    bf16x8 a0A[4], b0A[2], a0B[4], b0B[2], af1[4], bf1[2];
    f32x4 aE[4], aO[4];

    // --- prologue. Issue order: A0(4) A1(4) B0(2) B1(2) [waits+cvt]
    // A2(4) B2(2). vmcnt(8)->A0; vmcnt(4)->A1; vmcnt(6) final -> B0,B1
    // landed (newest 6 = A2+B2 in flight) = exact steady-state invariant.
    ISSUE_A(aE, 0); ISSUE_A(aO, 1);
    STAGE_B(0, 0);  STAGE_B(1, 1);
    asm volatile("s_waitcnt vmcnt(8)" ::: "memory");
    CVT_WRITE(aE, 0);
    asm volatile("s_waitcnt vmcnt(4)" ::: "memory");
    CVT_WRITE(aO, 1);
    ISSUE_A(aE, 2);
    STAGE_B(2, 2);
    asm volatile("s_waitcnt vmcnt(6)" ::: "memory");
    asm volatile("s_waitcnt lgkmcnt(0)" ::: "memory");
    __builtin_amdgcn_s_barrier();

    #pragma unroll
    for (int j = 0; j < 4; ++j)
        a0A[j] = *(const bf16x8*)(paBase + j * 256);
    #pragma unroll
    for (int q = 0; q < 2; ++q)
        b0A[q] = *(const bf16x8*)(pbBase + q * 256);

    // One slice = two windows.
    //  h0: read ks1 frags (slot c_) | issue A(s+3) f32 loads | 8 MFMA ks0 | bar
    //  h1: vmcnt(6) [A(s+2) regs ready, B(s+1) landed] | STAGE_B(s+3) |
    //      cvt+write A(s+2) -> slot (s+2)&3 | read slice s+1 ks0 frags
    //      (slot n_) | 8 MFMA ks1 | lgkmcnt(0) | bar
    // VMODE: 0 -> vmcnt(6); 1 -> vmcnt(2); 2 -> vmcnt(0); 3 -> none.
#define SLICE_BODY(s_, c_, n_, A0F, B0F, A0N, B0N, AIS, ACV,                   \
                   DOA, DOCVT, DOPF, DOB, VMODE)                               \
    do {                                                                       \
        _Pragma("unroll")                                                      \
        for (int j = 0; j < 4; ++j)                                            \
            af1[j] = *(const bf16x8*)(paBase + (c_) * SLOT + 4096 + j * 256);  \
        _Pragma("unroll")                                                      \
        for (int q = 0; q < 2; ++q)                                            \
            bf1[q] = *(const bf16x8*)(pbBase + (c_) * SLOT + 4096 + q * 256);  \
        if (DOA) ISSUE_A(AIS, (s_) + 3);                                       \
        __builtin_amdgcn_s_setprio(1);                                         \
        _Pragma("unroll")                                                      \
        for (int j = 0; j < 4; ++j)                                            \
            _Pragma("unroll")                                                  \
            for (int q = 0; q < 2; ++q)                                        \
                acc[j][q] = __builtin_amdgcn_mfma_f32_32x32x16_bf16(           \
                    A0F[j], B0F[q], acc[j][q], 0, 0, 0);                       \
        __builtin_amdgcn_s_setprio(0);                                         \
        __builtin_amdgcn_s_barrier();                                          \
        if ((VMODE) == 0) asm volatile("s_waitcnt vmcnt(6)" ::: "memory");     \
        else if ((VMODE) == 1) asm volatile("s_waitcnt vmcnt(2)" ::: "memory");\
        else if ((VMODE) == 2) asm volatile("s_waitcnt vmcnt(0)" ::: "memory");\
        if (DOB) STAGE_B(((s_) + 3) & 3, (s_) + 3);                            \
        if (DOCVT) CVT_WRITE(ACV, ((s_) + 2) & 3);                             \
        if (DOPF) {                                                            \
            _Pragma("unroll")                                                  \
            for (int j = 0; j < 4; ++j)                                        \
                A0N[j] = *(const bf16x8*)(paBase + (n_) * SLOT + j * 256);     \
            _Pragma("unroll")                                                  \
            for (int q = 0; q < 2; ++q)                                        \
                B0N[q] = *(const bf16x8*)(pbBase + (n_) * SLOT + q * 256);     \
        }                                                                      \
        __builtin_amdgcn_s_setprio(1);                                         \
        _Pragma("unroll")                                                      \
        for (int j = 0; j < 4; ++j)                                            \
            _Pragma("unroll")                                                  \
            for (int q = 0; q < 2; ++q)                                        \
                acc[j][q] = __builtin_amdgcn_mfma_f32_32x32x16_bf16(           \
                    af1[j], bf1[q], acc[j][q], 0, 0, 0);                       \
        __builtin_amdgcn_s_setprio(0);                                         \
        asm volatile("s_waitcnt lgkmcnt(0)" ::: "memory");                     \
        __builtin_amdgcn_s_barrier();                                          \
    } while (0)

    // --- main loop: 60 slices (ring 4 x reg ping-pong 2; A-set parity:
    // even s issues aO / cvts aE, odd s the reverse).
    #pragma unroll 1
    for (int s4 = 0; s4 < 15; ++s4) {
        const int s = s4 * 4;
        SLICE_BODY(s + 0, 0, 1, a0A, b0A, a0B, b0B, aO, aE, true, true, true, true, 0);
        SLICE_BODY(s + 1, 1, 2, a0B, b0B, a0A, b0A, aE, aO, true, true, true, true, 0);
        SLICE_BODY(s + 2, 2, 3, a0A, b0A, a0B, b0B, aO, aE, true, true, true, true, 0);
        SLICE_BODY(s + 3, 3, 0, a0B, b0B, a0A, b0A, aE, aO, true, true, true, true, 0);
    }
    // --- tail: slices 60..63. A-issue stops at 60 (A63 -> aO), cvt stops at
    // 61 (A63), B-stage stops at 60 (B63); vmcnt(2) at 61 (only A63+B63 may
    // fly), vmcnt(0) at 62 before reading slice-63 frags.
    SLICE_BODY(60, 0, 1, a0A, b0A, a0B, b0B, aO, aE, true,  true,  true,  true,  0);
    SLICE_BODY(61, 1, 2, a0B, b0B, a0A, b0A, aE, aO, false, true,  true,  false, 1);
    SLICE_BODY(62, 2, 3, a0A, b0A, a0B, b0B, aO, aE, false, false, true,  false, 2);
    SLICE_BODY(63, 3, 0, a0B, b0B, a0A, b0A, aE, aO, false, false, false, false, 3);

#undef SLICE_BODY
#undef STAGE_B
#undef CVT_WRITE
#undef ISSUE_A

    // --- epilogue: 32x32 C/D layout: col = lane&31,
    // row = (reg&3) + 8*(reg>>2) + 4*(lane>>5)
    float bv[2];
    #pragma unroll
    for (int q = 0; q < 2; ++q)
        bv[q] = bias[nBase + wn * 64 + q * 32 + l31];

    #pragma unroll
    for (int mt = 0; mt < 4; ++mt) {
        #pragma unroll
        for (int q = 0; q < 2; ++q) {
            const int col = nBase + wn * 64 + q * 32 + l31;
            #pragma unroll
            for (int r = 0; r < 16; ++r) {
                const int row = mBase + wm * 128 + mt * 32
                              + (r & 3) + 8 * (r >> 2) + 4 * lhi;
                C[(size_t)row * N + col] = acc[mt][q][r] + bv[q];
            }
        }
    }
}

extern "C" void kernel_launch(void* const* d_in, const int* in_sizes, int n_in,
                              void* d_out, int out_size, void* d_ws, size_t ws_size,
                              hipStream_t stream) {
    const float* x      = (const float*)d_in[0];  // [B][Cin][8]
    const float* weight = (const float*)d_in[1];  // [Cout][Cin][8]
    const float* bias   = (const float*)d_in[2];  // [Cout][8]
    const float* cayley = (const float*)d_in[3];  // [8][8][8]
    float* out = (float*)d_out;                   // [B][Cout][8]

    const int Cout = in_sizes[2] / 8;
    const int Cin  = in_sizes[1] / (Cout * 8);
    const int Bm   = in_sizes[0] / (Cin * 8);
    const int M = Bm;          // 8192
    const int N = Cout * 8;    // 2048
    const int K = Cin * 8;     // 2048

    __bf16* Wt2 = (__bf16*)d_ws;   // N*K bf16 = 8 MB, blocked layout

    // 1) fold only (X cast eliminated -- GEMM stages A from f32 directly)
    int foldBlocks = Cin * (N / 256);   // 2048
    fold_kernel<<<foldBlocks, 256, 0, stream>>>(weight, cayley, Wt2, Cin, N, K);

    // 2) GEMM: 256x256 tiles, 32 x 8 = 256 blocks, 512 threads (8 waves)
    int grid = (M / BM) * (N / BN);
    gemm_bt_kernel<<<grid, 512, 0, stream>>>(x, Wt2, bias, out, M, N, K);
}

// Round 8
// 181.353 us; speedup vs baseline: 1.0871x; 1.0871x over previous
//
#include <hip/hip_runtime.h>
#include <stdint.h>
#include <stddef.h>

// CliffordLinear as one bf16 GEMM:
//   out[b, o*8+l] = sum_{i,k} X[b, i*8+k] * Wt[o*8+l, i*8+k] + bias[o*8+l]
//   Wt[(o,l),(i,k)] = sum_j cayley[j,k,l] * W[o,i,j]
// M=8192, N=2048, K=2048. bf16 MFMA 16x16x32, fp32 accumulate.
//
// R14: exact port of the m201 8-phase 256^2 template (the harness-verified
// 1563 TF structure), replacing my invented K-slice ring (R8-R12, all 72-77
// us / MfmaUtil 37%). R13's in-GEMM cast is reverted (it regressed: bank
// conflicts + A-latency on the critical path); prep = R9's verified
// cast+fold. R13 did establish: non-GEMM overhead is ~85 us fixed + ~17 us
// cast -> the GEMM is the only real lever.
//
// Structure: BM=BN=256, BK=64, 512 thr (8 waves, wm=w>>2, wn=w&3).
// LDS = AS[2 buf][2 half][128x64] + BS same = 128 KB. KEY: per-wave rows =
// mh*128 + wm*64 + mf*16 + l16 -> A-half == quadrant mh for ALL waves (same
// for B/nh), so each phase touches exactly one A-half + one B-half.
// 8 phases / 2 K-tiles, snake (A0B0, A0B1, A1B1, A1B0 | buf1 same); per
// phase: {ds-read new subtile (4/8/12 x b128) | stage 1 half-tile (2 x
// global_load_lds 16B/thread) | barrier | lgkmcnt(0) | setprio(1) | 16 MFMA
// | setprio(0) | [vmcnt(6) at P4/P8 only] | barrier}.
// Stage map (iter t, kt=2t): P1: b1.B0<-kt+1 (read at P5 this iter, lands
// by P4's vmcnt); P2-P5: b0.{A0,B1,A1,B0}<-kt+2; P6-P8: b1.{A0,B1,A1}<-kt+3.
// Ledger: at P4-end vmcnt(6) lands prev{P6,P7,P8}+P1 = exactly buf1's 4
// halves read at P5-P8; at P8-end lands P2-P5 = buf0 kt+2's 4 halves.
// Dest-free proof: each stage target's last LDS-read is >=1 phase earlier
// (drained at that phase's lgkmcnt(0) before its MFMA).
// Swizzle (both-sides involution, rule #21): stage SOURCE pre-swizzled
// colE = ((i&7)^(i>>3))*8; read group = (kk*4+quad)^(l16&7). Verified:
// LDS elem rowL*64 + ((kk*4+quad)^(rowL&7))*8 holds logical (rowL, kk*32+
// quad*8+e) on both paths; each bank-group gets exactly 8 lanes (uniform =
// conflict-free for wave64 b128).

typedef __bf16 bf16x8 __attribute__((ext_vector_type(8)));
typedef float  f32x4  __attribute__((ext_vector_type(4)));

#define BM 256
#define BN 256

__device__ __forceinline__ void async_copy16(void* lds_dst, const void* g_src) {
    __builtin_amdgcn_global_load_lds(
        (__attribute__((address_space(1))) void*)g_src,
        (__attribute__((address_space(3))) void*)lds_dst,
        16, 0, 0);
}

// ---------------- kernel 1: fused prep (cast X -> bf16, fold Cayley) -------
// (R9-verified.) blocks [0, castBlocks): cast; rest: fold.
__global__ __launch_bounds__(256) void prep_kernel(
    const float* __restrict__ x, __bf16* __restrict__ Xb, long nx,
    const float* __restrict__ W, const float* __restrict__ cayley,
    __bf16* __restrict__ Wt, int Cin, int Cout, int castBlocks)
{
    __shared__ float Cay[512];
    if ((int)blockIdx.x < castBlocks) {
        long i = ((long)blockIdx.x * 256 + threadIdx.x) * 8;
        if (i + 8 <= nx) {
            const f32x4* p = (const f32x4*)(x + i);
            f32x4 v0 = p[0];
            f32x4 v1 = p[1];
            bf16x8 o;
            o[0] = (__bf16)v0[0]; o[1] = (__bf16)v0[1];
            o[2] = (__bf16)v0[2]; o[3] = (__bf16)v0[3];
            o[4] = (__bf16)v1[0]; o[5] = (__bf16)v1[1];
            o[6] = (__bf16)v1[2]; o[7] = (__bf16)v1[3];
            *(bf16x8*)(Xb + i) = o;
        }
        return;
    }
    for (int t = threadIdx.x; t < 512; t += 256) Cay[t] = cayley[t];
    __syncthreads();

    int flat = (blockIdx.x - castBlocks) * 256 + threadIdx.x;  // n*Cin + i
    int total = Cout * 8 * Cin;
    if (flat >= total) return;
    int i = flat % Cin;
    int n = flat / Cin;
    int o = n >> 3, l = n & 7;

    const float* wrow = W + ((size_t)o * Cin + i) * 8;
    float w8[8];
    #pragma unroll
    for (int j = 0; j < 8; ++j) w8[j] = wrow[j];

    bf16x8 outv;
    #pragma unroll
    for (int k = 0; k < 8; ++k) {
        float s = 0.f;
        #pragma unroll
        for (int j = 0; j < 8; ++j) s += Cay[j * 64 + k * 8 + l] * w8[j];
        outv[k] = (__bf16)s;
    }
    *(bf16x8*)(Wt + (size_t)n * (Cin * 8) + i * 8) = outv;
}

// ---------------- kernel 2: bf16 GEMM, m201 8-phase ------------------------
__global__ __launch_bounds__(512, 2) void gemm_bt_kernel(
    const __bf16* __restrict__ A,
    const __bf16* __restrict__ Bt,
    const float*  __restrict__ bias,
    float* __restrict__ C,
    int M, int N, int K)
{
    // [buf][half][128 rows][64 cols] each; flattened. 64 KB + 64 KB.
    __shared__ __align__(16) __bf16 AS[2 * 2 * 8192];
    __shared__ __align__(16) __bf16 BS[2 * 2 * 8192];

    const int tid  = threadIdx.x;
    const int wave = tid >> 6;    // 0..7
    const int lane = tid & 63;
    const int quad = lane >> 4;   // 0..3
    const int l16  = lane & 15;   // 0..15

    // --- XCD swizzle: 256 blocks, 8 XCDs; bijective since 256%8==0.
    const int bid = blockIdx.x;
    const int xcd = bid & 7;
    const int idx = bid >> 3;                 // 0..31
    const int mBase = (xcd * 4 + (idx & 3)) * BM;
    const int nBase = (idx >> 2) * BN;

    // --- staging: half-tile = 16 chunks of 1024 B; wave w owns chunks
    // 2w, 2w+1. Lane i: row = c*8 + (i>>3), source col pre-swizzled
    // colE = ((i&7)^(i>>3))*8 elems (involution with the read swizzle).
    const int rsub = lane >> 3;                    // 0..7
    const int colE = ((lane & 7) ^ rsub) * 8;      // elems within 64-col tile
    const int c0 = 2 * wave, c1 = 2 * wave + 1;
    const __bf16* pA0 = A  + (size_t)(mBase + c0 * 8 + rsub) * K + colE;
    const __bf16* pA1 = A  + (size_t)(mBase + c1 * 8 + rsub) * K + colE;
    const __bf16* pB0 = Bt + (size_t)(nBase + c0 * 8 + rsub) * K + colE;
    const __bf16* pB1 = Bt + (size_t)(nBase + c1 * 8 + rsub) * K + colE;

#define STAGE_A(SB, SH, SKT) do {                                              \
        async_copy16(&AS[((SB) * 2 + (SH)) * 8192 + c0 * 512],                 \
                     pA0 + (size_t)(SH) * 128 * K + (size_t)(SKT) * 64);       \
        async_copy16(&AS[((SB) * 2 + (SH)) * 8192 + c1 * 512],                 \
                     pA1 + (size_t)(SH) * 128 * K + (size_t)(SKT) * 64);       \
    } while (0)
#define STAGE_B(SB, SH, SKT) do {                                              \
        async_copy16(&BS[((SB) * 2 + (SH)) * 8192 + c0 * 512],                 \
                     pB0 + (size_t)(SH) * 128 * K + (size_t)(SKT) * 64);       \
        async_copy16(&BS[((SB) * 2 + (SH)) * 8192 + c1 * 512],                 \
                     pB1 + (size_t)(SH) * 128 * K + (size_t)(SKT) * 64);       \
    } while (0)

    // --- compute: wave (wm,wn); rows = mh*128 + wm*64 + mf*16 + l16,
    // cols = nh*128 + wn*32 + nf*16 + l16. Read swizzle: group =
    // (kk*4+quad) ^ (l16&7); elem addr = rowL*64 + group*8 (kk XOR = ^32).
    const int wm = wave >> 2;     // 0..1
    const int wn = wave & 3;      // 0..3
    const int aRd = wm * 4096 + l16 * 64 + ((quad ^ (l16 & 7)) * 8);
    const int bRd = wn * 2048 + l16 * 64 + ((quad ^ (l16 & 7)) * 8);

    f32x4 acc[8][4] = {};
    bf16x8 af[4][2], bfr[2][2];

#define PHASE(BUF, MH, NH, RDA, RDB, ST, SB, SH, SKT, VM)                      \
    do {                                                                       \
        if (RDA) {                                                             \
            _Pragma("unroll")                                                  \
            for (int mf = 0; mf < 4; ++mf)                                     \
                _Pragma("unroll")                                              \
                for (int kk = 0; kk < 2; ++kk)                                 \
                    af[mf][kk] = *(const bf16x8*)(AS + ((BUF)*2+(MH))*8192     \
                                    + ((aRd ^ (kk*32)) + mf*1024));            \
        }                                                                      \
        if (RDB) {                                                             \
            _Pragma("unroll")                                                  \
            for (int nf = 0; nf < 2; ++nf)                                     \
                _Pragma("unroll")                                              \
                for (int kk = 0; kk < 2; ++kk)                                 \
                    bfr[nf][kk] = *(const bf16x8*)(BS + ((BUF)*2+(NH))*8192    \
                                    + ((bRd ^ (kk*32)) + nf*1024));            \
        }                                                                      \
        if ((ST) == 1) STAGE_A(SB, SH, SKT);                                   \
        else if ((ST) == 2) STAGE_B(SB, SH, SKT);                              \
        __builtin_amdgcn_s_barrier();                                          \
        asm volatile("s_waitcnt lgkmcnt(0)" ::: "memory");                     \
        __builtin_amdgcn_s_setprio(1);                                         \
        _Pragma("unroll")                                                      \
        for (int mf = 0; mf < 4; ++mf)                                         \
            _Pragma("unroll")                                                  \
            for (int nf = 0; nf < 2; ++nf)                                     \
                _Pragma("unroll")                                              \
                for (int kk = 0; kk < 2; ++kk)                                 \
                    acc[(MH)*4+mf][(NH)*2+nf] =                                \
                        __builtin_amdgcn_mfma_f32_16x16x32_bf16(               \
                            af[mf][kk], bfr[nf][kk],                           \
                            acc[(MH)*4+mf][(NH)*2+nf], 0, 0, 0);               \
        __builtin_amdgcn_s_setprio(0);                                         \
        if ((VM) == 6)      asm volatile("s_waitcnt vmcnt(6)" ::: "memory");   \
        else if ((VM) == 0) asm volatile("s_waitcnt vmcnt(0)" ::: "memory");   \
        __builtin_amdgcn_s_barrier();                                          \
    } while (0)

    // --- prologue: stage b0{A0,B0,B1,A1}<-kt0, b1{A0,B1,A1}<-kt1 (7 halves,
    // 14 loads/thread). vmcnt(6) -> oldest 4 stages (all of b0) landed.
    STAGE_A(0, 0, 0); STAGE_B(0, 0, 0); STAGE_B(0, 1, 0); STAGE_A(0, 1, 0);
    STAGE_A(1, 0, 1); STAGE_B(1, 1, 1); STAGE_A(1, 1, 1);
    asm volatile("s_waitcnt vmcnt(6)" ::: "memory");
    __builtin_amdgcn_s_barrier();

    // --- main loop: iterations 0..14 (K-tiles 0..29 computed; stages reach
    // K-tile 2t+3 <= 31).
    #pragma unroll 1
    for (int t = 0; t < 15; ++t) {
        const int kt = 2 * t;
        PHASE(0, 0, 0, 1, 1, 2, 1, 0, kt + 1, -1);  // P1  + stage b1.B0
        PHASE(0, 0, 1, 0, 1, 1, 0, 0, kt + 2, -1);  // P2  + stage b0.A0
        PHASE(0, 1, 1, 1, 0, 2, 0, 1, kt + 2, -1);  // P3  + stage b0.B1
        PHASE(0, 1, 0, 0, 1, 1, 0, 1, kt + 2,  6);  // P4  + stage b0.A1
        PHASE(1, 0, 0, 1, 1, 2, 0, 0, kt + 2, -1);  // P5  + stage b0.B0
        PHASE(1, 0, 1, 0, 1, 1, 1, 0, kt + 3, -1);  // P6  + stage b1.A0
        PHASE(1, 1, 1, 1, 0, 2, 1, 1, kt + 3, -1);  // P7  + stage b1.B1
        PHASE(1, 1, 0, 0, 1, 1, 1, 1, kt + 3,  6);  // P8  + stage b1.A1
    }
    // --- tail iteration (kt=30,31): only P1's stage (b1.B0<-31, read at P5);
    // vmcnt(0) at P4 drains it; no further stages/waits.
    PHASE(0, 0, 0, 1, 1, 2, 1, 0, 31, -1);
    PHASE(0, 0, 1, 0, 1, 0, 0, 0, 0, -1);
    PHASE(0, 1, 1, 1, 0, 0, 0, 0, 0, -1);
    PHASE(0, 1, 0, 0, 1, 0, 0, 0, 0,  0);
    PHASE(1, 0, 0, 1, 1, 0, 0, 0, 0, -1);
    PHASE(1, 0, 1, 0, 1, 0, 0, 0, 0, -1);
    PHASE(1, 1, 1, 1, 0, 0, 0, 0, 0, -1);
    PHASE(1, 1, 0, 0, 1, 0, 0, 0, 0, -1);
    asm volatile("s_waitcnt vmcnt(0)" ::: "memory");

#undef PHASE
#undef STAGE_A
#undef STAGE_B

    // --- epilogue: C/D layout col = l16, row = quad*4 + r (per 16x16 frag).
    float bv[4];
    #pragma unroll
    for (int bj = 0; bj < 4; ++bj)
        bv[bj] = bias[nBase + (bj >> 1) * 128 + wn * 32 + (bj & 1) * 16 + l16];

    #pragma unroll
    for (int ai = 0; ai < 8; ++ai) {
        const int row0 = mBase + (ai >> 2) * 128 + wm * 64 + (ai & 3) * 16
                       + quad * 4;
        #pragma unroll
        for (int bj = 0; bj < 4; ++bj) {
            const int col = nBase + (bj >> 1) * 128 + wn * 32 + (bj & 1) * 16
                          + l16;
            #pragma unroll
            for (int r = 0; r < 4; ++r)
                C[(size_t)(row0 + r) * N + col] = acc[ai][bj][r] + bv[bj];
        }
    }
}

extern "C" void kernel_launch(void* const* d_in, const int* in_sizes, int n_in,
                              void* d_out, int out_size, void* d_ws, size_t ws_size,
                              hipStream_t stream) {
    const float* x      = (const float*)d_in[0];  // [B][Cin][8]
    const float* weight = (const float*)d_in[1];  // [Cout][Cin][8]
    const float* bias   = (const float*)d_in[2];  // [Cout][8]
    const float* cayley = (const float*)d_in[3];  // [8][8][8]
    float* out = (float*)d_out;                   // [B][Cout][8]

    const int Cout = in_sizes[2] / 8;
    const int Cin  = in_sizes[1] / (Cout * 8);
    const int Bm   = in_sizes[0] / (Cin * 8);
    const int M = Bm;          // 8192
    const int N = Cout * 8;    // 2048
    const int K = Cin * 8;     // 2048

    __bf16* Xb = (__bf16*)d_ws;                               // M*K bf16 = 32 MB
    __bf16* Wt = (__bf16*)((char*)d_ws + (size_t)M * K * 2);  // N*K bf16 = 8 MB

    // 1) fused prep: cast X + fold Cayley into Wt, one dispatch
    long nx = (long)M * K;
    int castBlocks = (int)(nx / 8 / 256);               // nx divisible by 2048
    int foldBlocks = (N * Cin + 255) / 256;
    prep_kernel<<<castBlocks + foldBlocks, 256, 0, stream>>>(
        x, Xb, nx, weight, cayley, Wt, Cin, Cout, castBlocks);

    // 2) GEMM: 256x256 tiles, 32 x 8 = 256 blocks, 512 threads (8 waves)
    int grid = (M / BM) * (N / BN);
    gemm_bt_kernel<<<grid, 512, 0, stream>>>(Xb, Wt, bias, out, M, N, K);
}